// Round 15
// baseline (136.105 us; speedup 1.0000x reference)
//
#include <hip/hip_runtime.h>

constexpr int N = 8192;
// MIN_DIST = RADIUS*2*scale = 1.0f;  TRI = N(N+1)/2, exact in f32
constexpr float TRI = 33558528.0f;

// Diagnostic repeat factors: force pair/corr dispatches above the 39us
// fillBuffer floor so rocprof top-5 finally shows their counters.
// Idempotent: each rep recomputes and rewrites identical values.
constexpr int REP_PAIR = 4;
constexpr int REP_CORR = 16;

__device__ __forceinline__ float fsqrt(float v) { return __builtin_amdgcn_sqrtf(v); }

// ws layout: p4[N] (float4) | row_sd[N] | row_sm[N] | row_corr[N] | partials[32*5]

__global__ __launch_bounds__(256)
void pack_kernel(const float* __restrict__ x, const float* __restrict__ y,
                 const float* __restrict__ z, float4* __restrict__ p4) {
    const int i = blockIdx.x * 256 + threadIdx.x;
    p4[i] = make_float4(x[i], y[i], z[i], 0.f);
}

// 1024 blocks: R7 pair section, verbatim inner loop, wrapped in REP_PAIR.
__global__ __launch_bounds__(256, 8)
void pair_kernel(const float4* __restrict__ p4,
                 float* __restrict__ row_sd, float* __restrict__ row_sm) {
    const int tid  = threadIdx.x;
    const int lane = tid & 63;
    const int wave = tid >> 6;
    const int b       = blockIdx.x;
    const int topBase = 4 * b;            // 0..4092
    const int botBase = N - 4 * (b + 1);  // 8188..4096

    float xr[8], yr[8], zr[8];
#pragma unroll
    for (int r = 0; r < 4; ++r) {
        const float4 pt = p4[topBase + r];
        const float4 pb = p4[botBase + r];
        xr[r]     = pt.x; yr[r]     = pt.y; zr[r]     = pt.z;
        xr[4 + r] = pb.x; yr[4 + r] = pb.y; zr[4 + r] = pb.z;
    }
    __shared__ float lsd[4][8];
    __shared__ float lsm[4][8];

#pragma unroll 1
    for (int rep = 0; rep < REP_PAIR; ++rep) {
        float sd[8], sm[8];
#pragma unroll
        for (int r = 0; r < 8; ++r) { sd[r] = 0.f; sm[r] = 0.f; }

#pragma unroll
        for (int g = 0; g < 2; ++g) {
            const int base = g ? botBase : topBase;
            const int ro   = g * 4;

            // head chunk [base, base+256): predicated vs diagonal and N
            {
                const int    j  = base + tid;
                const int    jc = (j < N) ? j : (N - 1);
                const float4 p  = p4[jc];
#pragma unroll
                for (int r = 0; r < 4; ++r) {
                    const float dx = p.x - xr[ro + r], dy = p.y - yr[ro + r], dz = p.z - zr[ro + r];
                    const float d  = fsqrt(dx * dx + dy * dy + dz * dz);
                    if (j < N && tid >= r) { sd[ro + r] += d; sm[ro + r] += fminf(d, 1.f); }
                }
            }
            // full middle 256-chunks: predicate-free, preloaded
            int j0 = base + 256;
            if (j0 + 256 <= N) {
                float4 p = p4[j0 + tid];
                while (true) {
                    const float4 c    = p;
                    const bool   more = (j0 + 512 <= N);
                    if (more) p = p4[j0 + 256 + tid];
#pragma unroll
                    for (int r = 0; r < 4; ++r) {
                        const float dx = c.x - xr[ro + r], dy = c.y - yr[ro + r], dz = c.z - zr[ro + r];
                        const float d  = fsqrt(dx * dx + dy * dy + dz * dz);
                        sd[ro + r] += d; sm[ro + r] += fminf(d, 1.f);
                    }
                    j0 += 256;
                    if (!more) break;
                }
            }
            // tail partial chunk
            if (j0 < N) {
                const int j = j0 + tid;
                if (j < N) {
                    const float4 p = p4[j];
#pragma unroll
                    for (int r = 0; r < 4; ++r) {
                        const float dx = p.x - xr[ro + r], dy = p.y - yr[ro + r], dz = p.z - zr[ro + r];
                        const float d  = fsqrt(dx * dx + dy * dy + dz * dz);
                        sd[ro + r] += d; sm[ro + r] += fminf(d, 1.f);
                    }
                }
            }
        }

#pragma unroll
        for (int r = 0; r < 8; ++r) {
            float a = sd[r], c = sm[r];
#pragma unroll
            for (int off = 32; off; off >>= 1) {
                a += __shfl_down(a, off);
                c += __shfl_down(c, off);
            }
            if (lane == 0) { lsd[wave][r] = a; lsm[wave][r] = c; }
        }
        __syncthreads();
        if (tid < 8) {
            const float a = lsd[0][tid] + lsd[1][tid] + lsd[2][tid] + lsd[3][tid];
            const float c = lsm[0][tid] + lsm[1][tid] + lsm[2][tid] + lsm[3][tid];
            const int   i = (tid < 4) ? (topBase + tid) : (botBase + tid - 4);
            row_sd[i] = a;
            row_sm[i] = c;
        }
        __syncthreads();   // lsd/lsm reusable next rep
    }
}

// 1024 blocks: R7 corr section, verbatim, wrapped in REP_CORR.
__global__ __launch_bounds__(256, 8)
void corr_kernel(const float4* __restrict__ p4, float* __restrict__ row_corr) {
    const int tid  = threadIdx.x;
    const int lane = tid & 63;
    const int wave = tid >> 6;
    const int cb   = blockIdx.x;

#pragma unroll 1
    for (int rep = 0; rep < REP_CORR; ++rep) {
#pragma unroll
        for (int rr = 0; rr < 2; ++rr) {
            const int    i  = 8 * cb + 2 * wave + rr;
            const float4 pi = p4[i];
            float corr = 0.f;
            int   jb   = i;
            float4 a  = p4[min(jb + lane,      N - 1)];
            float4 bq = p4[min(jb + 64 + lane, N - 1)];
            while (true) {
                const float4 na = p4[min(jb + 128 + lane, N - 1)];
                const float4 nb = p4[min(jb + 192 + lane, N - 1)];
                const int j0i = jb + lane, j1i = jb + 64 + lane;
                float dx = a.x - pi.x, dy = a.y - pi.y, dz = a.z - pi.z;
                const float d0 = fsqrt(dx * dx + dy * dy + dz * dz);
                dx = bq.x - pi.x; dy = bq.y - pi.y; dz = bq.z - pi.z;
                const float d1 = fsqrt(dx * dx + dy * dy + dz * dz);
                const unsigned long long m0 = __ballot(j0i >= N || d0 > 1.f);
                const unsigned long long m1 = __ballot(j1i >= N || d1 > 1.f);
                int stop;
                if (m0)      stop = __builtin_ctzll(m0);
                else if (m1) stop = 64 + __builtin_ctzll(m1);
                else         stop = 128;
                if (lane < stop)      corr += 1.f - d0;
                if (64 + lane < stop) corr += 1.f - d1;
                if (stop < 128) break;
                jb += 128;
                a = na; bq = nb;
            }
#pragma unroll
            for (int off = 32; off; off >>= 1) corr += __shfl_down(corr, off);
            if (lane == 0) row_corr[i] = corr;
        }
    }
}

// 32 blocks: per-block partial sums of {A, M, C, fix, noise}
__global__ __launch_bounds__(256)
void partial_kernel(const float* __restrict__ y, const float* __restrict__ z,
                    const float* __restrict__ row_sd, const float* __restrict__ row_sm,
                    const float* __restrict__ row_corr, float* __restrict__ partials) {
    const int tid = threadIdx.x;
    const int i   = blockIdx.x * 256 + tid;
    float v[5];
    v[0] = row_sd[i];
    v[1] = row_sm[i];
    v[2] = row_corr[i];
    const float yv = y[i], zv = z[i];
    v[3] = fmaxf(yv - 1.f, 0.f) + fmaxf(-1.f - yv, 0.f)
         + fmaxf(zv - 1.f, 0.f) + fmaxf(-1.f - zv, 0.f);
    v[4] = 0.f;
    if (i < N - 2) {
        const float d2y = y[i + 2] - 2.f * y[i + 1] + y[i];
        const float d2z = z[i + 2] - 2.f * z[i + 1] + z[i];
        v[4] = d2y * d2y + d2z * d2z;
    }
    const int lane = tid & 63, wave = tid >> 6;
    __shared__ float s[4][5];
#pragma unroll
    for (int c = 0; c < 5; ++c) {
        float a = v[c];
#pragma unroll
        for (int off = 32; off; off >>= 1) a += __shfl_down(a, off);
        if (lane == 0) s[wave][c] = a;
    }
    __syncthreads();
    if (tid == 0) {
#pragma unroll
        for (int c = 0; c < 5; ++c)
            partials[blockIdx.x * 5 + c] = s[0][c] + s[1][c] + s[2][c] + s[3][c];
    }
}

// 1 block: final 32-way reduce + loss assembly
__global__ __launch_bounds__(64)
void final_kernel(const float* __restrict__ partials, float* __restrict__ out) {
    const int tid = threadIdx.x;
    float a[5] = {0.f, 0.f, 0.f, 0.f, 0.f};
    if (tid < 32) {
#pragma unroll
        for (int c = 0; c < 5; ++c) a[c] = partials[tid * 5 + c];
    }
#pragma unroll
    for (int c = 0; c < 5; ++c) {
#pragma unroll
        for (int off = 16; off; off >>= 1) a[c] += __shfl_down(a[c], off, 32);
    }
    if (tid == 0) {
        const float A = a[0], M = a[1], C = a[2], fix = a[3], noise = a[4];
        out[0] = fix + (2.f * A) / 10000.f
               + (2.f * (TRI - M) - (float)N - C) + 10.f * noise;
    }
}

extern "C" void kernel_launch(void* const* d_in, const int* in_sizes, int n_in,
                              void* d_out, int out_size, void* d_ws, size_t ws_size,
                              hipStream_t stream) {
    const float* x = (const float*)d_in[0];
    const float* y = (const float*)d_in[1];
    const float* z = (const float*)d_in[2];
    float* out      = (float*)d_out;
    float4* p4      = (float4*)d_ws;
    float* row_sd   = (float*)(p4 + N);
    float* row_sm   = row_sd + N;
    float* row_corr = row_sm + N;
    float* partials = row_corr + N;

    pack_kernel<<<N / 256, 256, 0, stream>>>(x, y, z, p4);
    pair_kernel<<<1024, 256, 0, stream>>>(p4, row_sd, row_sm);
    corr_kernel<<<1024, 256, 0, stream>>>(p4, row_corr);
    partial_kernel<<<32, 256, 0, stream>>>(y, z, row_sd, row_sm, row_corr, partials);
    final_kernel<<<1, 64, 0, stream>>>(partials, out);
}

// Round 16
// 39.992 us; speedup vs baseline: 3.4033x; 3.4033x over previous
//
#include <hip/hip_runtime.h>

constexpr int N = 8192;
// MIN_DIST = RADIUS*2*scale = 1.0f;  TRI = N(N+1)/2, exact in f32
constexpr float TRI = 33558528.0f;

__device__ __forceinline__ float fsqrt(float v) { return __builtin_amdgcn_sqrtf(v); }
__device__ __forceinline__ float sgpr(float v) {
    return __int_as_float(__builtin_amdgcn_readfirstlane(__float_as_int(v)));
}

// ws layout: p4[N] (float4) | row_sd[N] | row_sm[N] | row_corr[N]

__global__ __launch_bounds__(256)
void pack_kernel(const float* __restrict__ x, const float* __restrict__ y,
                 const float* __restrict__ z, float4* __restrict__ p4) {
    const int i = blockIdx.x * 256 + threadIdx.x;
    p4[i] = make_float4(x[i], y[i], z[i], 0.f);
}

// 2048 blocks:
//  [0,1024):    pair tiles — rows {4b..4b+3} (top) + {N-4b-4..N-4b-1} (bot),
//               j >= i sweep, DEPTH-2 prefetch (pA/pB in flight), row coords
//               pinned to SGPRs via readfirstlane.
//  [1024,2048): masked-prefix-run correction (R7 structure, verbatim).
__global__ __launch_bounds__(256, 8)
void main_kernel(const float4* __restrict__ p4,
                 float* __restrict__ row_sd, float* __restrict__ row_sm,
                 float* __restrict__ row_corr) {
    const int tid  = threadIdx.x;
    const int lane = tid & 63;
    const int wave = tid >> 6;

    if (blockIdx.x < 1024) {
        const int b       = blockIdx.x;
        const int topBase = 4 * b;            // 0..4092
        const int botBase = N - 4 * (b + 1);  // 8188..4096

        // Row coordinates -> SGPRs (block-uniform, exact) to keep VGPRs free
        // for the two in-flight prefetch registers.
        float xr[8], yr[8], zr[8];
#pragma unroll
        for (int r = 0; r < 4; ++r) {
            const float4 pt = p4[topBase + r];
            const float4 pb = p4[botBase + r];
            xr[r]     = sgpr(pt.x); yr[r]     = sgpr(pt.y); zr[r]     = sgpr(pt.z);
            xr[4 + r] = sgpr(pb.x); yr[4 + r] = sgpr(pb.y); zr[4 + r] = sgpr(pb.z);
        }
        float sd[8], sm[8];
#pragma unroll
        for (int r = 0; r < 8; ++r) { sd[r] = 0.f; sm[r] = 0.f; }

#pragma unroll
        for (int g = 0; g < 2; ++g) {
            const int base = g ? botBase : topBase;
            const int ro   = g * 4;

            auto body = [&](const float4& c) {
#pragma unroll
                for (int r = 0; r < 4; ++r) {
                    const float dx = c.x - xr[ro + r], dy = c.y - yr[ro + r], dz = c.z - zr[ro + r];
                    const float d  = fsqrt(dx * dx + dy * dy + dz * dz);
                    sd[ro + r] += d; sm[ro + r] += fminf(d, 1.f);
                }
            };

            // head chunk [base, base+256): predicated vs diagonal and N
            {
                const int    j  = base + tid;
                const int    jc = (j < N) ? j : (N - 1);
                const float4 p  = p4[jc];
#pragma unroll
                for (int r = 0; r < 4; ++r) {
                    const float dx = p.x - xr[ro + r], dy = p.y - yr[ro + r], dz = p.z - zr[ro + r];
                    const float d  = fsqrt(dx * dx + dy * dy + dz * dz);
                    if (j < N && tid >= r) { sd[ro + r] += d; sm[ro + r] += fminf(d, 1.f); }
                }
            }

            // full middle chunks with depth-2 prefetch (static names, no arrays)
            const int first = base + 256;
            const int nfull = (N - first) / 256;   // >= 0
            float4 pA, pB;
            if (nfull >= 1) pA = p4[first + tid];
            if (nfull >= 2) pB = p4[first + 256 + tid];
            int t = 0;
            for (; t + 2 <= nfull; t += 2) {
                {
                    const float4 c = pA;
                    if (t + 2 < nfull) pA = p4[first + (t + 2) * 256 + tid];
                    body(c);
                }
                {
                    const float4 c = pB;
                    if (t + 3 < nfull) pB = p4[first + (t + 3) * 256 + tid];
                    body(c);
                }
            }
            if (t < nfull) body(pA);               // odd leftover full chunk

            // tail partial chunk
            const int j0 = first + nfull * 256;
            if (j0 < N) {
                const int j = j0 + tid;
                if (j < N) {
                    const float4 p = p4[j];
#pragma unroll
                    for (int r = 0; r < 4; ++r) {
                        const float dx = p.x - xr[ro + r], dy = p.y - yr[ro + r], dz = p.z - zr[ro + r];
                        const float d  = fsqrt(dx * dx + dy * dy + dz * dz);
                        sd[ro + r] += d; sm[ro + r] += fminf(d, 1.f);
                    }
                }
            }
        }

        __shared__ float lsd[4][8];
        __shared__ float lsm[4][8];
#pragma unroll
        for (int r = 0; r < 8; ++r) {
            float a = sd[r], c = sm[r];
#pragma unroll
            for (int off = 32; off; off >>= 1) {
                a += __shfl_down(a, off);
                c += __shfl_down(c, off);
            }
            if (lane == 0) { lsd[wave][r] = a; lsm[wave][r] = c; }
        }
        __syncthreads();
        if (tid < 8) {
            const float a = lsd[0][tid] + lsd[1][tid] + lsd[2][tid] + lsd[3][tid];
            const float c = lsm[0][tid] + lsm[1][tid] + lsm[2][tid] + lsm[3][tid];
            const int   i = (tid < 4) ? (topBase + tid) : (botBase + tid - 4);
            row_sd[i] = a;
            row_sm[i] = c;
        }
    } else {
        // corr: 8 rows/block, 2 rows/wave, 128-j windows, speculative preload
        const int cb = blockIdx.x - 1024;
#pragma unroll
        for (int rr = 0; rr < 2; ++rr) {
            const int    i  = 8 * cb + 2 * wave + rr;
            const float4 pi = p4[i];
            float corr = 0.f;
            int   jb   = i;
            float4 a  = p4[min(jb + lane,      N - 1)];
            float4 bq = p4[min(jb + 64 + lane, N - 1)];
            while (true) {
                const float4 na = p4[min(jb + 128 + lane, N - 1)];
                const float4 nb = p4[min(jb + 192 + lane, N - 1)];
                const int j0i = jb + lane, j1i = jb + 64 + lane;
                float dx = a.x - pi.x, dy = a.y - pi.y, dz = a.z - pi.z;
                const float d0 = fsqrt(dx * dx + dy * dy + dz * dz);
                dx = bq.x - pi.x; dy = bq.y - pi.y; dz = bq.z - pi.z;
                const float d1 = fsqrt(dx * dx + dy * dy + dz * dz);
                const unsigned long long m0 = __ballot(j0i >= N || d0 > 1.f);
                const unsigned long long m1 = __ballot(j1i >= N || d1 > 1.f);
                int stop;
                if (m0)      stop = __builtin_ctzll(m0);
                else if (m1) stop = 64 + __builtin_ctzll(m1);
                else         stop = 128;
                if (lane < stop)      corr += 1.f - d0;
                if (64 + lane < stop) corr += 1.f - d1;
                if (stop < 128) break;
                jb += 128;
                a = na; bq = nb;
            }
#pragma unroll
            for (int off = 32; off; off >>= 1) corr += __shfl_down(corr, off);
            if (lane == 0) row_corr[i] = corr;
        }
    }
}

// Single block, deterministic: totals + O(N) terms + loss assembly.
//   A = sum row_sd, M = sum row_sm, C = sum row_corr
//   sum_dist = 2A;  sum_relu = 2*(TRI - M) - N;  intersect = sum_relu - C
__global__ __launch_bounds__(256)
void reduce_kernel(const float* __restrict__ y, const float* __restrict__ z,
                   const float* __restrict__ row_sd, const float* __restrict__ row_sm,
                   const float* __restrict__ row_corr, float* __restrict__ out) {
    const int tid = threadIdx.x;
    float A = 0.f, M = 0.f, C = 0.f, fix = 0.f, noise = 0.f;
    for (int i = tid; i < N; i += 256) {
        A += row_sd[i];
        M += row_sm[i];
        C += row_corr[i];
        const float yv = y[i], zv = z[i];
        fix += fmaxf(yv - 1.f, 0.f) + fmaxf(-1.f - yv, 0.f)
             + fmaxf(zv - 1.f, 0.f) + fmaxf(-1.f - zv, 0.f);
        if (i < N - 2) {
            const float d2y = y[i + 2] - 2.f * y[i + 1] + y[i];
            const float d2z = z[i + 2] - 2.f * z[i + 1] + z[i];
            noise += d2y * d2y + d2z * d2z;
        }
    }
    __shared__ float s[5][4];
    const int lane = tid & 63, wave = tid >> 6;
    float v[5] = {A, M, C, fix, noise};
#pragma unroll
    for (int c = 0; c < 5; ++c) {
#pragma unroll
        for (int off = 32; off; off >>= 1) v[c] += __shfl_down(v[c], off);
        if (lane == 0) s[c][wave] = v[c];
    }
    __syncthreads();
    if (tid == 0) {
        float t[5];
#pragma unroll
        for (int c = 0; c < 5; ++c) t[c] = s[c][0] + s[c][1] + s[c][2] + s[c][3];
        out[0] = t[3] + (2.f * t[0]) / 10000.f
               + (2.f * (TRI - t[1]) - (float)N - t[2]) + 10.f * t[4];
    }
}

extern "C" void kernel_launch(void* const* d_in, const int* in_sizes, int n_in,
                              void* d_out, int out_size, void* d_ws, size_t ws_size,
                              hipStream_t stream) {
    const float* x = (const float*)d_in[0];
    const float* y = (const float*)d_in[1];
    const float* z = (const float*)d_in[2];
    float* out      = (float*)d_out;
    float4* p4      = (float4*)d_ws;
    float* row_sd   = (float*)(p4 + N);
    float* row_sm   = row_sd + N;
    float* row_corr = row_sm + N;

    pack_kernel<<<N / 256, 256, 0, stream>>>(x, y, z, p4);
    main_kernel<<<2048, 256, 0, stream>>>(p4, row_sd, row_sm, row_corr);
    reduce_kernel<<<1, 256, 0, stream>>>(y, z, row_sd, row_sm, row_corr, out);
}

// Round 17
// 30.842 us; speedup vs baseline: 4.4130x; 1.2967x over previous
//
#include <hip/hip_runtime.h>

constexpr int N = 8192;
// MIN_DIST = RADIUS*2*scale = 1.0f;  TRI = N(N+1)/2, exact in f32
constexpr float TRI = 33558528.0f;

__device__ __forceinline__ float fsqrt(float v) { return __builtin_amdgcn_sqrtf(v); }

// ws layout: p4[N] (float4) | row_sd[N] | row_sm[N] | row_corr[N]

__global__ __launch_bounds__(256)
void pack_kernel(const float* __restrict__ x, const float* __restrict__ y,
                 const float* __restrict__ z, float4* __restrict__ p4) {
    const int i = blockIdx.x * 256 + threadIdx.x;
    p4[i] = make_float4(x[i], y[i], z[i], 0.f);
}

// 2048 blocks:
//  [0,1024):    pair tiles — rows {4b..4b+3} (top) + {N-4b-4..N-4b-1} (bot),
//               j >= i sweep on the packed stream. R7 structure VERBATIM
//               (proven 29.3us optimum; do not perturb).
//  [1024,2048): masked-prefix-run correction: 2 rows per wave processed
//               CONCURRENTLY in 128-j windows (same loads serve both rows)
//               -> half the serial latency exposures of the sequential form.
__global__ __launch_bounds__(256, 8)
void main_kernel(const float4* __restrict__ p4,
                 float* __restrict__ row_sd, float* __restrict__ row_sm,
                 float* __restrict__ row_corr) {
    const int tid  = threadIdx.x;
    const int lane = tid & 63;
    const int wave = tid >> 6;

    if (blockIdx.x < 1024) {
        const int b       = blockIdx.x;
        const int topBase = 4 * b;            // 0..4092
        const int botBase = N - 4 * (b + 1);  // 8188..4096

        float xr[8], yr[8], zr[8];
#pragma unroll
        for (int r = 0; r < 4; ++r) {
            const float4 pt = p4[topBase + r];
            const float4 pb = p4[botBase + r];
            xr[r]     = pt.x; yr[r]     = pt.y; zr[r]     = pt.z;
            xr[4 + r] = pb.x; yr[4 + r] = pb.y; zr[4 + r] = pb.z;
        }
        float sd[8], sm[8];
#pragma unroll
        for (int r = 0; r < 8; ++r) { sd[r] = 0.f; sm[r] = 0.f; }

#pragma unroll
        for (int g = 0; g < 2; ++g) {
            const int base = g ? botBase : topBase;
            const int ro   = g * 4;

            // head chunk [base, base+256): predicated vs diagonal and N
            {
                const int    j  = base + tid;
                const int    jc = (j < N) ? j : (N - 1);
                const float4 p  = p4[jc];
#pragma unroll
                for (int r = 0; r < 4; ++r) {
                    const float dx = p.x - xr[ro + r], dy = p.y - yr[ro + r], dz = p.z - zr[ro + r];
                    const float d  = fsqrt(dx * dx + dy * dy + dz * dz);
                    if (j < N && tid >= r) { sd[ro + r] += d; sm[ro + r] += fminf(d, 1.f); }
                }
            }
            // full middle 256-chunks: predicate-free, preloaded
            int j0 = base + 256;
            if (j0 + 256 <= N) {
                float4 p = p4[j0 + tid];
                while (true) {
                    const float4 c    = p;
                    const bool   more = (j0 + 512 <= N);
                    if (more) p = p4[j0 + 256 + tid];
#pragma unroll
                    for (int r = 0; r < 4; ++r) {
                        const float dx = c.x - xr[ro + r], dy = c.y - yr[ro + r], dz = c.z - zr[ro + r];
                        const float d  = fsqrt(dx * dx + dy * dy + dz * dz);
                        sd[ro + r] += d; sm[ro + r] += fminf(d, 1.f);
                    }
                    j0 += 256;
                    if (!more) break;
                }
            }
            // tail partial chunk
            if (j0 < N) {
                const int j = j0 + tid;
                if (j < N) {
                    const float4 p = p4[j];
#pragma unroll
                    for (int r = 0; r < 4; ++r) {
                        const float dx = p.x - xr[ro + r], dy = p.y - yr[ro + r], dz = p.z - zr[ro + r];
                        const float d  = fsqrt(dx * dx + dy * dy + dz * dz);
                        sd[ro + r] += d; sm[ro + r] += fminf(d, 1.f);
                    }
                }
            }
        }

        __shared__ float lsd[4][8];
        __shared__ float lsm[4][8];
#pragma unroll
        for (int r = 0; r < 8; ++r) {
            float a = sd[r], c = sm[r];
#pragma unroll
            for (int off = 32; off; off >>= 1) {
                a += __shfl_down(a, off);
                c += __shfl_down(c, off);
            }
            if (lane == 0) { lsd[wave][r] = a; lsm[wave][r] = c; }
        }
        __syncthreads();
        if (tid < 8) {
            const float a = lsd[0][tid] + lsd[1][tid] + lsd[2][tid] + lsd[3][tid];
            const float c = lsm[0][tid] + lsm[1][tid] + lsm[2][tid] + lsm[3][tid];
            const int   i = (tid < 4) ? (topBase + tid) : (botBase + tid - 4);
            row_sd[i] = a;
            row_sm[i] = c;
        }
    } else {
        // corr: rows i0 = 8cb+2w and i1 = i0+1 scanned CONCURRENTLY from the
        // diagonal in 128-j windows (2 loads in flight, speculative preload).
        // Run r: [i_r, stop_r), stop_r = first j >= i_r with d > 1 (or N).
        const int cb = blockIdx.x - 1024;
        const int i0 = 8 * cb + 2 * wave;
        const int i1 = i0 + 1;
        const float4 pi0 = p4[i0];
        const float4 pi1 = p4[i1];
        float c0 = 0.f, c1 = 0.f;
        bool  a0 = true, a1 = true;
        int   jb = i0;
        float4 A  = p4[min(jb + lane,      N - 1)];
        float4 B  = p4[min(jb + 64 + lane, N - 1)];
        while (a0 || a1) {
            const float4 nA = p4[min(jb + 128 + lane, N - 1)];
            const float4 nB = p4[min(jb + 192 + lane, N - 1)];
            const int jA = jb + lane, jB = jb + 64 + lane;

            float dx = A.x - pi0.x, dy = A.y - pi0.y, dz = A.z - pi0.z;
            const float d0A = fsqrt(dx * dx + dy * dy + dz * dz);
            dx = B.x - pi0.x; dy = B.y - pi0.y; dz = B.z - pi0.z;
            const float d0B = fsqrt(dx * dx + dy * dy + dz * dz);
            dx = A.x - pi1.x; dy = A.y - pi1.y; dz = A.z - pi1.z;
            const float d1A = fsqrt(dx * dx + dy * dy + dz * dz);
            dx = B.x - pi1.x; dy = B.y - pi1.y; dz = B.z - pi1.z;
            const float d1B = fsqrt(dx * dx + dy * dy + dz * dz);

            const unsigned long long m0A = __ballot(jA >= N || d0A > 1.f);
            const unsigned long long m0B = __ballot(jB >= N || d0B > 1.f);
            const unsigned long long m1A = __ballot(jA >= N || (jA >= i1 && d1A > 1.f));
            const unsigned long long m1B = __ballot(jB >= N || (jB >= i1 && d1B > 1.f));

            if (a0) {
                const int s0 = m0A ? __builtin_ctzll(m0A)
                                   : (m0B ? 64 + __builtin_ctzll(m0B) : 128);
                if (lane < s0)      c0 += 1.f - d0A;
                if (64 + lane < s0) c0 += 1.f - d0B;
                if (s0 < 128) a0 = false;
            }
            if (a1) {
                const int s1 = m1A ? __builtin_ctzll(m1A)
                                   : (m1B ? 64 + __builtin_ctzll(m1B) : 128);
                if (lane < s1      && jA >= i1) c1 += 1.f - d1A;
                if (64 + lane < s1 && jB >= i1) c1 += 1.f - d1B;
                if (s1 < 128) a1 = false;
            }
            jb += 128;
            A = nA; B = nB;
        }
#pragma unroll
        for (int off = 32; off; off >>= 1) {
            c0 += __shfl_down(c0, off);
            c1 += __shfl_down(c1, off);
        }
        if (lane == 0) { row_corr[i0] = c0; row_corr[i1] = c1; }
    }
}

// Single block, 1024 threads, deterministic: totals + O(N) terms + assembly.
//   A = sum row_sd, M = sum row_sm, C = sum row_corr
//   sum_dist = 2A;  sum_relu = 2*(TRI - M) - N;  intersect = sum_relu - C
__global__ __launch_bounds__(1024)
void reduce_kernel(const float* __restrict__ y, const float* __restrict__ z,
                   const float* __restrict__ row_sd, const float* __restrict__ row_sm,
                   const float* __restrict__ row_corr, float* __restrict__ out) {
    const int tid = threadIdx.x;
    float A = 0.f, M = 0.f, C = 0.f, fix = 0.f, noise = 0.f;
    // row arrays as float4: 8192/4 = 2048 float4s, 1024 threads -> 2 iters
#pragma unroll
    for (int it = 0; it < 2; ++it) {
        const int i4 = it * 1024 + tid;
        const float4 vd = ((const float4*)row_sd)[i4];
        const float4 vm = ((const float4*)row_sm)[i4];
        const float4 vc = ((const float4*)row_corr)[i4];
        A += (vd.x + vd.y) + (vd.z + vd.w);
        M += (vm.x + vm.y) + (vm.z + vm.w);
        C += (vc.x + vc.y) + (vc.z + vc.w);
    }
    // O(N) terms: 8 scalar iters
    for (int i = tid; i < N; i += 1024) {
        const float yv = y[i], zv = z[i];
        fix += fmaxf(yv - 1.f, 0.f) + fmaxf(-1.f - yv, 0.f)
             + fmaxf(zv - 1.f, 0.f) + fmaxf(-1.f - zv, 0.f);
        if (i < N - 2) {
            const float d2y = y[i + 2] - 2.f * y[i + 1] + y[i];
            const float d2z = z[i + 2] - 2.f * z[i + 1] + z[i];
            noise += d2y * d2y + d2z * d2z;
        }
    }
    __shared__ float s[5][16];
    const int lane = tid & 63, wave = tid >> 6;
    float v[5] = {A, M, C, fix, noise};
#pragma unroll
    for (int c = 0; c < 5; ++c) {
#pragma unroll
        for (int off = 32; off; off >>= 1) v[c] += __shfl_down(v[c], off);
        if (lane == 0) s[c][wave] = v[c];
    }
    __syncthreads();
    if (tid == 0) {
        float t[5];
#pragma unroll
        for (int c = 0; c < 5; ++c) {
            float acc = 0.f;
#pragma unroll
            for (int w = 0; w < 16; ++w) acc += s[c][w];
            t[c] = acc;
        }
        out[0] = t[3] + (2.f * t[0]) / 10000.f
               + (2.f * (TRI - t[1]) - (float)N - t[2]) + 10.f * t[4];
    }
}

extern "C" void kernel_launch(void* const* d_in, const int* in_sizes, int n_in,
                              void* d_out, int out_size, void* d_ws, size_t ws_size,
                              hipStream_t stream) {
    const float* x = (const float*)d_in[0];
    const float* y = (const float*)d_in[1];
    const float* z = (const float*)d_in[2];
    float* out      = (float*)d_out;
    float4* p4      = (float4*)d_ws;
    float* row_sd   = (float*)(p4 + N);
    float* row_sm   = row_sd + N;
    float* row_corr = row_sm + N;

    pack_kernel<<<N / 256, 256, 0, stream>>>(x, y, z, p4);
    main_kernel<<<2048, 256, 0, stream>>>(p4, row_sd, row_sm, row_corr);
    reduce_kernel<<<1, 1024, 0, stream>>>(y, z, row_sd, row_sm, row_corr, out);
}